// Round 1
// baseline (561.682 us; speedup 1.0000x reference)
//
#include <hip/hip_runtime.h>
#include <cstdint>
#include <cstddef>

typedef unsigned short u16;
typedef __bf16 bf16x8 __attribute__((ext_vector_type(8)));
typedef float  f32x4  __attribute__((ext_vector_type(8/2)));   // 4 floats
typedef u16    u16x8v __attribute__((ext_vector_type(8)));

#define EPS 1e-6f
#define BM 128
#define BN 128
#define BK 32

// ---------- helpers ----------
__device__ __forceinline__ u16 f2bf(float f) {
  union { float f; unsigned int u; } v; v.f = f;
  unsigned int u = v.u + 0x7FFFu + ((v.u >> 16) & 1u);   // RNE
  return (u16)(u >> 16);
}
__device__ __forceinline__ float bf2f(u16 h) {
  union { unsigned int u; float f; } v; v.u = ((unsigned int)h) << 16;
  return v.f;
}
__device__ __forceinline__ void async16(const void* g, void* l) {
  __builtin_amdgcn_global_load_lds(
      (const __attribute__((address_space(1))) void*)g,
      (__attribute__((address_space(3))) void*)l, 16, 0, 0);
}

// ---------- fp32 -> bf16 conversion ----------
__global__ __launch_bounds__(256) void cvt_bf16_kernel(
    const float* __restrict__ in, u16* __restrict__ out, int n8) {
  int i = blockIdx.x * 256 + threadIdx.x;
  if (i >= n8) return;
  const float4* p = (const float4*)in;
  float4 a = p[2 * (size_t)i], b = p[2 * (size_t)i + 1];
  u16x8v o;
  o[0] = f2bf(a.x); o[1] = f2bf(a.y); o[2] = f2bf(a.z); o[3] = f2bf(a.w);
  o[4] = f2bf(b.x); o[5] = f2bf(b.y); o[6] = f2bf(b.z); o[7] = f2bf(b.w);
  *(u16x8v*)(out + 8 * (size_t)i) = o;
}

// ---------- NT GEMM: C[M,N] = A[M,K] * B[N,K]^T + bias, opt phi ----------
// m97-style: 128x128 tile, BK=32, global_load_lds width 16, 16x16x32 bf16 MFMA.
template <int ACT, typename OutT>
__global__ __launch_bounds__(256) void gemm_nt(
    const u16* __restrict__ A, const u16* __restrict__ Bm,
    const float* __restrict__ bias, OutT* __restrict__ C,
    int M, int N, int K) {
  __shared__ u16 sA[BM * BK];
  __shared__ u16 sB[BN * BK];

  const int tid  = threadIdx.x;
  const int wave = tid >> 6;
  const int lane = tid & 63;
  const int bm = blockIdx.x * BM;
  const int bn = blockIdx.y * BN;
  const int wm = (wave & 1) * 64;
  const int wn = (wave >> 1) * 64;

  f32x4 acc[4][4] = {};

  // staging: each wave issues 2 A + 2 B global_load_lds (64 lanes x 16B = 16 rows each)
  const int kc = (lane & 3) * 8;
  const u16* gA0 = A  + (size_t)(bm + wave * 32 + (lane >> 2)) * K + kc;
  const u16* gB0 = Bm + (size_t)(bn + wave * 32 + (lane >> 2)) * K + kc;
  u16* lA0 = &sA[(wave * 32) * BK];
  u16* lA1 = &sA[(wave * 32 + 16) * BK];
  u16* lB0 = &sB[(wave * 32) * BK];
  u16* lB1 = &sB[(wave * 32 + 16) * BK];
  const size_t row16 = (size_t)16 * K;

  for (int k0 = 0; k0 < K; k0 += BK) {
    __syncthreads();
    async16(gA0 + k0,         lA0);
    async16(gA0 + k0 + row16, lA1);
    async16(gB0 + k0,         lB0);
    async16(gB0 + k0 + row16, lB1);
    __syncthreads();   // drains vmcnt -> LDS ready

    bf16x8 af[4], bfv[4];
#pragma unroll
    for (int i = 0; i < 4; i++)
      af[i] = *(const bf16x8*)&sA[(wm + i * 16 + (lane & 15)) * BK + (lane >> 4) * 8];
#pragma unroll
    for (int i = 0; i < 4; i++)
      bfv[i] = *(const bf16x8*)&sB[(wn + i * 16 + (lane & 15)) * BK + (lane >> 4) * 8];
#pragma unroll
    for (int mi = 0; mi < 4; mi++)
#pragma unroll
      for (int ni = 0; ni < 4; ni++)
        acc[mi][ni] = __builtin_amdgcn_mfma_f32_16x16x32_bf16(
            af[mi], bfv[ni], acc[mi][ni], 0, 0, 0);
  }

  // epilogue: C/D layout col=lane&15, row=(lane>>4)*4+reg
  const int r0 = (lane >> 4) * 4;
  const int cc = lane & 15;
#pragma unroll
  for (int ni = 0; ni < 4; ni++) {
    const int col = bn + wn + ni * 16 + cc;
    const float bv = bias[col];
#pragma unroll
    for (int mi = 0; mi < 4; mi++) {
#pragma unroll
      for (int j = 0; j < 4; j++) {
        const int row = bm + wm + mi * 16 + r0 + j;
        float val = acc[mi][ni][j] + bv;
        if (ACT) val = (val > 0.f) ? (val + 1.f) : __expf(val);  // phi = elu+1
        if constexpr (sizeof(OutT) == 2)
          C[(size_t)row * N + col] = (OutT)f2bf(val);
        else
          C[(size_t)row * N + col] = (OutT)val;
      }
    }
  }
}

// ---------- kv[bh][d][m] = sum_t K[t,d]*V[t,m]; ksum[bh][d] = sum_t K[t,d] ----------
// grid (8 chunks, 64 bh), block 256. fp32 atomics into zeroed workspace.
__global__ __launch_bounds__(256) void kv_ksum_kernel(
    const u16* __restrict__ Kb, const u16* __restrict__ Vb,
    float* __restrict__ kv, float* __restrict__ ksum) {
  const int bh = blockIdx.y;
  const int chunk = blockIdx.x;
  const int b = bh >> 4, h = bh & 15;
  const int tid = threadIdx.x;
  const int d = tid & 63;
  const int mg = tid >> 6;           // 0..3 -> m base mg*16

  __shared__ float sk[16][64];
  __shared__ float sv[16][64];

  float4 a0 = {0, 0, 0, 0}, a1 = a0, a2 = a0, a3 = a0;
  float ks = 0.f;

  const size_t rowBase = (size_t)b * 4096 + (size_t)chunk * 512;
  const int colBase = h * 64;

  for (int t0 = 0; t0 < 512; t0 += 16) {
    __syncthreads();
    for (int i = tid; i < 1024; i += 256) {
      const int tt = i >> 6, dd = i & 63;
      const size_t g = (rowBase + t0 + tt) * 1024 + colBase + dd;
      sk[tt][dd] = bf2f(Kb[g]);
      sv[tt][dd] = bf2f(Vb[g]);
    }
    __syncthreads();
#pragma unroll
    for (int tt = 0; tt < 16; tt++) {
      const float kd = sk[tt][d];
      if (mg == 0) ks += kd;
      const float4* vp = (const float4*)&sv[tt][mg * 16];
      const float4 v0 = vp[0], v1 = vp[1], v2 = vp[2], v3 = vp[3];
      a0.x += kd * v0.x; a0.y += kd * v0.y; a0.z += kd * v0.z; a0.w += kd * v0.w;
      a1.x += kd * v1.x; a1.y += kd * v1.y; a1.z += kd * v1.z; a1.w += kd * v1.w;
      a2.x += kd * v2.x; a2.y += kd * v2.y; a2.z += kd * v2.z; a2.w += kd * v2.w;
      a3.x += kd * v3.x; a3.y += kd * v3.y; a3.z += kd * v3.z; a3.w += kd * v3.w;
    }
  }
  float* kvp = kv + ((size_t)bh * 64 + d) * 64 + mg * 16;
  atomicAdd(kvp + 0,  a0.x); atomicAdd(kvp + 1,  a0.y);
  atomicAdd(kvp + 2,  a0.z); atomicAdd(kvp + 3,  a0.w);
  atomicAdd(kvp + 4,  a1.x); atomicAdd(kvp + 5,  a1.y);
  atomicAdd(kvp + 6,  a1.z); atomicAdd(kvp + 7,  a1.w);
  atomicAdd(kvp + 8,  a2.x); atomicAdd(kvp + 9,  a2.y);
  atomicAdd(kvp + 10, a2.z); atomicAdd(kvp + 11, a2.w);
  atomicAdd(kvp + 12, a3.x); atomicAdd(kvp + 13, a3.y);
  atomicAdd(kvp + 14, a3.z); atomicAdd(kvp + 15, a3.w);
  if (mg == 0) atomicAdd(ksum + (size_t)bh * 64 + d, ks);
}

// ---------- attn[t, h*64+m] = (Q[t,:] @ kv) * z[t] ----------
// grid (64 t-tiles, 64 bh), block 256. MFMA 16x16x32, kv transposed to bf16 in LDS.
#define QST 80   // padded LDS row stride (u16): 160B rows, 16B-aligned, 4-way banks
__global__ __launch_bounds__(256) void attn_apply_kernel(
    const u16* __restrict__ Qb, const float* __restrict__ kv,
    const float* __restrict__ ksum, u16* __restrict__ attn) {
  const int bh = blockIdx.y;
  const int tt = blockIdx.x;
  const int b = bh >> 4, h = bh & 15;
  const int tid = threadIdx.x, wave = tid >> 6, lane = tid & 63;

  __shared__ u16 skvT[64 * QST];   // [m][d] = kv[d][m] as bf16
  __shared__ u16 sq[64 * QST];     // [t][d]
  __shared__ float sz[64];
  __shared__ float sks[64];

  if (tid < 64) sks[tid] = ksum[(size_t)bh * 64 + tid] + EPS;

  const float* kvp = kv + (size_t)bh * 4096;
  for (int i = tid; i < 4096; i += 256) {
    const int dd = i >> 6, mm = i & 63;
    skvT[mm * QST + dd] = f2bf(kvp[i]);
  }
  const size_t qbase = ((size_t)b * 4096 + (size_t)tt * 64) * 1024 + h * 64;
  for (int i = tid; i < 4096; i += 256) {
    const int r = i >> 6, dd = i & 63;
    sq[r * QST + dd] = Qb[qbase + (size_t)r * 1024 + dd];
  }
  __syncthreads();

  if (tid < 64) {
    float za = 0.f;
#pragma unroll
    for (int j = 0; j < 64; j++) {
      const int dd = (j + tid) & 63;   // rotate to dodge bank conflicts
      za += bf2f(sq[tid * QST + dd]) * sks[dd];
    }
    sz[tid] = 1.f / (za + EPS);
  }
  __syncthreads();

  f32x4 acc[4] = {};
#pragma unroll
  for (int ks2 = 0; ks2 < 2; ks2++) {
    const bf16x8 a = *(const bf16x8*)&sq[(wave * 16 + (lane & 15)) * QST + ks2 * 32 + (lane >> 4) * 8];
#pragma unroll
    for (int ni = 0; ni < 4; ni++) {
      const bf16x8 bv = *(const bf16x8*)&skvT[(ni * 16 + (lane & 15)) * QST + ks2 * 32 + (lane >> 4) * 8];
      acc[ni] = __builtin_amdgcn_mfma_f32_16x16x32_bf16(a, bv, acc[ni], 0, 0, 0);
    }
  }

  const int r0 = (lane >> 4) * 4, cc = lane & 15;
#pragma unroll
  for (int ni = 0; ni < 4; ni++) {
#pragma unroll
    for (int j = 0; j < 4; j++) {
      const int r = wave * 16 + r0 + j;
      const int c = ni * 16 + cc;
      const float val = acc[ni][j] * sz[r];
      attn[qbase + (size_t)r * 1024 + c] = f2bf(val);
    }
  }
}

// ---------- launch ----------
extern "C" void kernel_launch(void* const* d_in, const int* in_sizes, int n_in,
                              void* d_out, int out_size, void* d_ws, size_t ws_size,
                              hipStream_t stream) {
  (void)in_sizes; (void)n_in; (void)out_size; (void)ws_size;
  const float* x  = (const float*)d_in[0];
  const float* Wq = (const float*)d_in[1];
  const float* bq = (const float*)d_in[2];
  const float* Wk = (const float*)d_in[3];
  const float* bk = (const float*)d_in[4];
  const float* Wv = (const float*)d_in[5];
  const float* bv = (const float*)d_in[6];
  const float* Wo = (const float*)d_in[7];
  const float* bo = (const float*)d_in[8];

  // B=4, T=4096, D=1024, H=16, DK=64; M = B*T = 16384
  char* ws = (char*)d_ws;
  u16* xb   = (u16*)ws;  ws += 33554432;               // [16384,1024] bf16
  u16* wqb  = (u16*)ws;  ws += 2097152;
  u16* wkb  = (u16*)ws;  ws += 2097152;
  u16* wvb  = (u16*)ws;  ws += 2097152;
  u16* wob  = (u16*)ws;  ws += 2097152;
  u16* Vb   = (u16*)ws;  ws += 33554432;
  u16* attn = (u16*)ws;  ws += 33554432;
  float* kvb  = (float*)ws; ws += 1048576;             // [64][64][64] fp32
  float* ksum = (float*)ws; ws += 16384;               // [64][64] fp32

  // park Q,K (bf16) in d_out: exactly 2 x 33.5MB = 67MB = out bytes
  u16* Qb = (u16*)d_out;
  u16* Kb = Qb + 16777216;

  hipMemsetAsync(kvb, 0, 1048576 + 16384, stream);     // zero kv + ksum

  cvt_bf16_kernel<<<8192, 256, 0, stream>>>(x,  xb,  2097152);
  cvt_bf16_kernel<<<512,  256, 0, stream>>>(Wq, wqb, 131072);
  cvt_bf16_kernel<<<512,  256, 0, stream>>>(Wk, wkb, 131072);
  cvt_bf16_kernel<<<512,  256, 0, stream>>>(Wv, wvb, 131072);
  cvt_bf16_kernel<<<512,  256, 0, stream>>>(Wo, wob, 131072);

  dim3 gg(128, 8), blk(256);
  gemm_nt<1, u16><<<gg, blk, 0, stream>>>(xb, wqb, bq, Qb, 16384, 1024, 1024);
  gemm_nt<1, u16><<<gg, blk, 0, stream>>>(xb, wkb, bk, Kb, 16384, 1024, 1024);
  gemm_nt<0, u16><<<gg, blk, 0, stream>>>(xb, wvb, bv, Vb, 16384, 1024, 1024);

  kv_ksum_kernel<<<dim3(8, 64), blk, 0, stream>>>(Kb, Vb, kvb, ksum);
  attn_apply_kernel<<<dim3(64, 64), blk, 0, stream>>>(Qb, kvb, ksum, attn);

  gemm_nt<0, float><<<gg, blk, 0, stream>>>(attn, wob, bo, (float*)d_out,
                                            16384, 1024, 1024);
}

// Round 2
// 413.226 us; speedup vs baseline: 1.3593x; 1.3593x over previous
//
#include <hip/hip_runtime.h>
#include <cstdint>
#include <cstddef>

typedef unsigned short u16;
typedef __bf16 bf16x8 __attribute__((ext_vector_type(8)));
typedef float  f32x4  __attribute__((ext_vector_type(4)));
typedef u16    u16x8v __attribute__((ext_vector_type(8)));
typedef u16    u16x4  __attribute__((ext_vector_type(4)));

#define EPS 1e-6f
#define BM 128
#define BN 128
#define BK 32

// ---------- helpers ----------
__device__ __forceinline__ u16 f2bf(float f) {
  union { float f; unsigned int u; } v; v.f = f;
  unsigned int u = v.u + 0x7FFFu + ((v.u >> 16) & 1u);   // RNE
  return (u16)(u >> 16);
}
__device__ __forceinline__ float bf2f(u16 h) {
  union { unsigned int u; float f; } v; v.u = ((unsigned int)h) << 16;
  return v.f;
}
__device__ __forceinline__ void async16(const void* g, void* l) {
  __builtin_amdgcn_global_load_lds(
      (const __attribute__((address_space(1))) void*)g,
      (__attribute__((address_space(3))) void*)l, 16, 0, 0);
}

// ---------- fp32 -> bf16 conversion ----------
__global__ __launch_bounds__(256) void cvt_bf16_kernel(
    const float* __restrict__ in, u16* __restrict__ out, int n8) {
  int i = blockIdx.x * 256 + threadIdx.x;
  if (i >= n8) return;
  const float4* p = (const float4*)in;
  float4 a = p[2 * (size_t)i], b = p[2 * (size_t)i + 1];
  u16x8v o;
  o[0] = f2bf(a.x); o[1] = f2bf(a.y); o[2] = f2bf(a.z); o[3] = f2bf(a.w);
  o[4] = f2bf(b.x); o[5] = f2bf(b.y); o[6] = f2bf(b.z); o[7] = f2bf(b.w);
  *(u16x8v*)(out + 8 * (size_t)i) = o;
}

// ---------- NT GEMM: C[M,N] = A[M,K] * B[N,K]^T + bias, opt phi ----------
template <int ACT, typename OutT>
__global__ __launch_bounds__(256) void gemm_nt(
    const u16* __restrict__ A, const u16* __restrict__ Bm,
    const float* __restrict__ bias, OutT* __restrict__ C,
    int M, int N, int K) {
  __shared__ u16 sA[BM * BK];
  __shared__ u16 sB[BN * BK];

  const int tid  = threadIdx.x;
  const int wave = tid >> 6;
  const int lane = tid & 63;
  const int bm = blockIdx.x * BM;
  const int bn = blockIdx.y * BN;
  const int wm = (wave & 1) * 64;
  const int wn = (wave >> 1) * 64;

  f32x4 acc[4][4] = {};

  const int kc = (lane & 3) * 8;
  const u16* gA0 = A  + (size_t)(bm + wave * 32 + (lane >> 2)) * K + kc;
  const u16* gB0 = Bm + (size_t)(bn + wave * 32 + (lane >> 2)) * K + kc;
  u16* lA0 = &sA[(wave * 32) * BK];
  u16* lA1 = &sA[(wave * 32 + 16) * BK];
  u16* lB0 = &sB[(wave * 32) * BK];
  u16* lB1 = &sB[(wave * 32 + 16) * BK];
  const size_t row16 = (size_t)16 * K;

  for (int k0 = 0; k0 < K; k0 += BK) {
    __syncthreads();
    async16(gA0 + k0,         lA0);
    async16(gA0 + k0 + row16, lA1);
    async16(gB0 + k0,         lB0);
    async16(gB0 + k0 + row16, lB1);
    __syncthreads();

    bf16x8 af[4], bfv[4];
#pragma unroll
    for (int i = 0; i < 4; i++)
      af[i] = *(const bf16x8*)&sA[(wm + i * 16 + (lane & 15)) * BK + (lane >> 4) * 8];
#pragma unroll
    for (int i = 0; i < 4; i++)
      bfv[i] = *(const bf16x8*)&sB[(wn + i * 16 + (lane & 15)) * BK + (lane >> 4) * 8];
#pragma unroll
    for (int mi = 0; mi < 4; mi++)
#pragma unroll
      for (int ni = 0; ni < 4; ni++)
        acc[mi][ni] = __builtin_amdgcn_mfma_f32_16x16x32_bf16(
            af[mi], bfv[ni], acc[mi][ni], 0, 0, 0);
  }

  const int r0 = (lane >> 4) * 4;
  const int cc = lane & 15;
#pragma unroll
  for (int ni = 0; ni < 4; ni++) {
    const int col = bn + wn + ni * 16 + cc;
    const float bv = bias[col];
#pragma unroll
    for (int mi = 0; mi < 4; mi++) {
#pragma unroll
      for (int j = 0; j < 4; j++) {
        const int row = bm + wm + mi * 16 + r0 + j;
        float val = acc[mi][ni][j] + bv;
        if (ACT) val = (val > 0.f) ? (val + 1.f) : __expf(val);  // phi = elu+1
        if constexpr (sizeof(OutT) == 2)
          C[(size_t)row * N + col] = (OutT)f2bf(val);
        else
          C[(size_t)row * N + col] = (OutT)val;
      }
    }
  }
}

// ---------- kv via MFMA: kv[bh][d][m] = sum_t K[t,d]*V[t,m]; ksum via ones-B ----------
// grid (8 chunks, 64 bh), block 256 = 4 waves. Each block: 512 timesteps, 8 stages of 64 t.
// LDS layout: s{K,V}T[row][col] with rotation col = (t + 8*(row>>3)) & 63 so that the
// transposed b64 writes spread across banks (~2-way, free) while frag reads stay b128.
__global__ __launch_bounds__(256) void kv_mfma_kernel(
    const u16* __restrict__ Kb, const u16* __restrict__ Vb,
    float* __restrict__ kv, float* __restrict__ ksum) {
  const int bh = blockIdx.y;
  const int chunk = blockIdx.x;
  const int b = bh >> 4, h = bh & 15;
  const int tid = threadIdx.x, wave = tid >> 6, lane = tid & 63;

  __shared__ u16 sKT[64 * 64];   // [d][t'] rotated
  __shared__ u16 sVT[64 * 64];   // [m][t'] rotated

  f32x4 acc[4] = {};    // 4 d-tiles x (my m-tile = wave)
  f32x4 accs[4] = {};   // wave 0: ksum via ones-B (every column = ksum)

  union { u16x8v u; bf16x8 b; } uo;
#pragma unroll
  for (int e = 0; e < 8; e++) uo.u[e] = 0x3F80;   // bf16 1.0
  const bf16x8 ones = uo.b;

  // staging assignment: threads 0..127 -> K, 128..255 -> V
  const int half = tid >> 7;          // 0=K, 1=V
  const int j    = tid & 127;
  const int tg   = j >> 3;            // 0..15 (4 t-rows each)
  const int dg   = j & 7;             // 0..7  (8 d-cols each)
  const u16* src = half ? Vb : Kb;
  u16* dst = half ? sVT : sKT;
  const int colb = (4 * tg + 8 * dg) & 63;   // rotated column base (mult of 4)

  const size_t rowBase = (size_t)b * 4096 + (size_t)chunk * 512;
  const size_t gbase = (rowBase + 4 * tg) * 1024 + (size_t)h * 64 + dg * 8;

  u16x8v pre[2][4];
#pragma unroll
  for (int s = 0; s < 4; s++)
    pre[0][s] = *(const u16x8v*)(src + gbase + (size_t)s * 1024);

#pragma unroll
  for (int st = 0; st < 8; st++) {
    const int cb = st & 1;
    __syncthreads();                 // prev stage's frag reads done
    // transposed write: 8 x ds_write_b64
#pragma unroll
    for (int e = 0; e < 8; e++) {
      u16x4 w;
      w[0] = pre[cb][0][e]; w[1] = pre[cb][1][e];
      w[2] = pre[cb][2][e]; w[3] = pre[cb][3][e];
      *(u16x4*)&dst[(dg * 8 + e) * 64 + colb] = w;
    }
    // prefetch next stage (overlaps MFMA below)
    if (st + 1 < 8) {
      const size_t nb = gbase + (size_t)(st + 1) * 64 * 1024;
#pragma unroll
      for (int s = 0; s < 4; s++)
        pre[cb ^ 1][s] = *(const u16x8v*)(src + nb + (size_t)s * 1024);
    }
    __syncthreads();                 // LDS ready

#pragma unroll
    for (int kst = 0; kst < 2; kst++) {
      const int q8 = kst * 32 + (lane >> 4) * 8;
      bf16x8 bfrag;
      {
        const int rr = wave * 16 + (lane & 15);
        const int c = (q8 + 8 * (rr >> 3)) & 63;
        bfrag = *(const bf16x8*)&sVT[rr * 64 + c];
      }
#pragma unroll
      for (int i = 0; i < 4; i++) {
        const int rr = i * 16 + (lane & 15);
        const int c = (q8 + 8 * (rr >> 3)) & 63;
        const bf16x8 afrag = *(const bf16x8*)&sKT[rr * 64 + c];
        acc[i] = __builtin_amdgcn_mfma_f32_16x16x32_bf16(afrag, bfrag, acc[i], 0, 0, 0);
        if (wave == 0)
          accs[i] = __builtin_amdgcn_mfma_f32_16x16x32_bf16(afrag, ones, accs[i], 0, 0, 0);
      }
    }
  }

  // C/D layout: col=lane&15, row=(lane>>4)*4+j
  const int r0 = (lane >> 4) * 4, cc = lane & 15;
  float* kvp = kv + (size_t)bh * 4096;
#pragma unroll
  for (int i = 0; i < 4; i++)
#pragma unroll
    for (int jj = 0; jj < 4; jj++)
      atomicAdd(&kvp[(size_t)(i * 16 + r0 + jj) * 64 + wave * 16 + cc], acc[i][jj]);
  if (wave == 0 && cc == 0) {
#pragma unroll
    for (int i = 0; i < 4; i++)
#pragma unroll
      for (int jj = 0; jj < 4; jj++)
        atomicAdd(&ksum[(size_t)bh * 64 + i * 16 + r0 + jj], accs[i][jj]);
  }
}

// ---------- attn[t, h*64+m] = (Q[t,:] @ kv) * z[t] ----------
#define QST 80
__global__ __launch_bounds__(256) void attn_apply_kernel(
    const u16* __restrict__ Qb, const float* __restrict__ kv,
    const float* __restrict__ ksum, u16* __restrict__ attn) {
  const int bh = blockIdx.y;
  const int tt = blockIdx.x;
  const int b = bh >> 4, h = bh & 15;
  const int tid = threadIdx.x, wave = tid >> 6, lane = tid & 63;

  __shared__ u16 skvT[64 * QST];   // [m][d] = kv[d][m] as bf16
  __shared__ u16 sq[64 * QST];     // [t][d]
  __shared__ float sz[64];
  __shared__ float sks[64];

  if (tid < 64) sks[tid] = ksum[(size_t)bh * 64 + tid] + EPS;

  const float* kvp = kv + (size_t)bh * 4096;
  for (int i = tid; i < 4096; i += 256) {
    const int dd = i >> 6, mm = i & 63;
    skvT[mm * QST + dd] = f2bf(kvp[i]);
  }
  const size_t qbase = ((size_t)b * 4096 + (size_t)tt * 64) * 1024 + h * 64;
  for (int i = tid; i < 4096; i += 256) {
    const int r = i >> 6, dd = i & 63;
    sq[r * QST + dd] = Qb[qbase + (size_t)r * 1024 + dd];
  }
  __syncthreads();

  if (tid < 64) {
    float za = 0.f;
#pragma unroll
    for (int j = 0; j < 64; j++) {
      const int dd = (j + tid) & 63;
      za += bf2f(sq[tid * QST + dd]) * sks[dd];
    }
    sz[tid] = 1.f / (za + EPS);
  }
  __syncthreads();

  f32x4 acc[4] = {};
#pragma unroll
  for (int ks2 = 0; ks2 < 2; ks2++) {
    const bf16x8 a = *(const bf16x8*)&sq[(wave * 16 + (lane & 15)) * QST + ks2 * 32 + (lane >> 4) * 8];
#pragma unroll
    for (int ni = 0; ni < 4; ni++) {
      const bf16x8 bv = *(const bf16x8*)&skvT[(ni * 16 + (lane & 15)) * QST + ks2 * 32 + (lane >> 4) * 8];
      acc[ni] = __builtin_amdgcn_mfma_f32_16x16x32_bf16(a, bv, acc[ni], 0, 0, 0);
    }
  }

  const int r0 = (lane >> 4) * 4, cc = lane & 15;
#pragma unroll
  for (int ni = 0; ni < 4; ni++) {
#pragma unroll
    for (int j = 0; j < 4; j++) {
      const int r = wave * 16 + r0 + j;
      const int c = ni * 16 + cc;
      const float val = acc[ni][j] * sz[r];
      attn[qbase + (size_t)r * 1024 + c] = f2bf(val);
    }
  }
}

// ---------- launch ----------
extern "C" void kernel_launch(void* const* d_in, const int* in_sizes, int n_in,
                              void* d_out, int out_size, void* d_ws, size_t ws_size,
                              hipStream_t stream) {
  (void)in_sizes; (void)n_in; (void)out_size; (void)ws_size;
  const float* x  = (const float*)d_in[0];
  const float* Wq = (const float*)d_in[1];
  const float* bq = (const float*)d_in[2];
  const float* Wk = (const float*)d_in[3];
  const float* bk = (const float*)d_in[4];
  const float* Wv = (const float*)d_in[5];
  const float* bv = (const float*)d_in[6];
  const float* Wo = (const float*)d_in[7];
  const float* bo = (const float*)d_in[8];

  // B=4, T=4096, D=1024, H=16, DK=64; M = B*T = 16384
  char* ws = (char*)d_ws;
  u16* xb   = (u16*)ws;  ws += 33554432;               // [16384,1024] bf16
  u16* wqb  = (u16*)ws;  ws += 2097152;
  u16* wkb  = (u16*)ws;  ws += 2097152;
  u16* wvb  = (u16*)ws;  ws += 2097152;
  u16* wob  = (u16*)ws;  ws += 2097152;
  u16* Vb   = (u16*)ws;  ws += 33554432;
  u16* attn = (u16*)ws;  ws += 33554432;
  float* kvb  = (float*)ws; ws += 1048576;             // [64][64][64] fp32
  float* ksum = (float*)ws; ws += 16384;               // [64][64] fp32

  u16* Qb = (u16*)d_out;
  u16* Kb = Qb + 16777216;

  hipMemsetAsync(kvb, 0, 1048576 + 16384, stream);

  cvt_bf16_kernel<<<8192, 256, 0, stream>>>(x,  xb,  2097152);
  cvt_bf16_kernel<<<512,  256, 0, stream>>>(Wq, wqb, 131072);
  cvt_bf16_kernel<<<512,  256, 0, stream>>>(Wk, wkb, 131072);
  cvt_bf16_kernel<<<512,  256, 0, stream>>>(Wv, wvb, 131072);
  cvt_bf16_kernel<<<512,  256, 0, stream>>>(Wo, wob, 131072);

  dim3 gg(128, 8), blk(256);
  gemm_nt<1, u16><<<gg, blk, 0, stream>>>(xb, wqb, bq, Qb, 16384, 1024, 1024);
  gemm_nt<1, u16><<<gg, blk, 0, stream>>>(xb, wkb, bk, Kb, 16384, 1024, 1024);
  gemm_nt<0, u16><<<gg, blk, 0, stream>>>(xb, wvb, bv, Vb, 16384, 1024, 1024);

  kv_mfma_kernel<<<dim3(8, 64), blk, 0, stream>>>(Kb, Vb, kvb, ksum);
  attn_apply_kernel<<<dim3(64, 64), blk, 0, stream>>>(Qb, kvb, ksum, attn);

  gemm_nt<0, float><<<gg, blk, 0, stream>>>(attn, wob, bo, (float*)d_out,
                                            16384, 1024, 1024);
}